// Round 17
// baseline (4213.615 us; speedup 1.0000x reference)
//
#include <hip/hip_runtime.h>

// ---------------------------------------------------------------------------
// v17 = v16 (best verified: 2682us) + ONE mechanism change: weight loads
// forced onto the VECTOR memory path (global_load_dword) instead of the
// scalar SMEM path (s_load).
//
// Why: r15/r16 proved FMA issue rate is not binding (25% fewer VALU ops ->
// only 3% gain). The residual 45% stall is SMEM wait structure: s_load
// returns are out-of-order -> compiler emits coarse lgkmcnt(0) drains with
// ~4-group look-ahead (SGPR-limited). VMEM returns are in-order -> fine
// vmcnt(N) pipelining, which the compiler already does deeply for taps.
// A uniform-address global_load is ONE broadcast L1 access; 9 issue slots
// per 72cy FMA block.
//
// Trick: opaque zero VGPR offset (asm "+v") makes the weight address
// formally divergent -> compiler cannot scalarize to s_load. All lanes
// read the same address -> broadcast. Addresses/order/accumulation chains
// unchanged -> bitwise identical.
//
// Dead ends measured this session (do not retry):
//  - LDS-staged weights (r4); weight repack (r7); ci-pair w[18] clump (r12)
//  - 2-deep tap prefetch (r3/r9); k4+pixconv fusion (r8)
//  - convoy __syncthreads (r11); P=6 (r13); packed CB=25 k4 (r15)
// ---------------------------------------------------------------------------

typedef float v2f __attribute__((ext_vector_type(2)));

// ---------------------------------------------------------------------------
// Packed variant: CB even. CB/2 j-pairs; weights via VMEM broadcast loads.
// ---------------------------------------------------------------------------
template<int CIN, int COUT, int CB, int P, int W>
__global__ __launch_bounds__(256, 2) void conv3x3_relu_pk(
    const float* __restrict__ in, const float* __restrict__ wt,
    float* __restrict__ out,
    int in_y0, int in_rows, int out_y0, int out_rows)
{
  static_assert(COUT % CB == 0 && (CB & 1) == 0, "even CB dividing COUT");
  constexpr int NCB = COUT / CB;
  constexpr int TW  = 64;
  constexpr int TH  = 4 * P;
  constexpr int CBP = CB / 2;

  const int n   = blockIdx.z / NCB;
  const int co0 = (blockIdx.z % NCB) * CB;
  const int lx  = threadIdx.x & 63;
  const int yg  = threadIdx.x >> 6;
  const int x0  = blockIdx.x * TW;
  const int x   = x0 + lx;
  const int oy0 = out_y0 + blockIdx.y * TH;
  const int yb  = yg * P;

  const int maxoff = in_rows * W * 4 - 4;

  // opaque zero: forces weight loads onto the VMEM path (no scalarization)
  int zoff = 0;
  asm("" : "+v"(zoff));

  int   voff[P + 2][3];
  float mrow[P + 2];
#pragma unroll
  for (int r = 0; r < P + 2; ++r) {
    int ry = oy0 + yb + r - 1 - in_y0;
    mrow[r] = (ry >= 0 && ry < in_rows) ? 1.f : 0.f;
    int ryc = ry < 0 ? 0 : (ry >= in_rows ? in_rows - 1 : ry);
    int vo  = (ryc * W + x) * 4;
    voff[r][1] = vo;
    voff[r][0] = (vo > 4 ? vo : 4) - 4;
    int vr = vo + 4;
    voff[r][2] = vr < maxoff ? vr : maxoff;
  }
  const float ml = (x == 0)     ? 0.f : 1.f;
  const float mr = (x == W - 1) ? 0.f : 1.f;

  const bool interior =
      (x0 > 0) && (x0 + TW < W) &&
      ((oy0 - 1 - in_y0) >= 0) && ((oy0 + TH - in_y0) < in_rows);

  v2f acc[CBP][P];
#pragma unroll
  for (int jj = 0; jj < CBP; ++jj)
#pragma unroll
    for (int p = 0; p < P; ++p) acc[jj][p] = (v2f){0.f, 0.f};

  const float* inN = in + (size_t)n * CIN * in_rows * W;
  const size_t chbytes = (size_t)in_rows * W * 4;

#pragma unroll 1
  for (int ci = 0; ci < CIN; ++ci) {
    const char* bp = (const char*)inN + (size_t)ci * chbytes;

    float va[P + 2][3];
#pragma unroll
    for (int r = 0; r < P + 2; ++r)
#pragma unroll
      for (int c = 0; c < 3; ++c)
        va[r][c] = *(const float*)(bp + voff[r][c]);

    if (!interior) {
#pragma unroll
      for (int r = 0; r < P + 2; ++r) {
#pragma unroll
        for (int c = 0; c < 3; ++c) {
          float m = mrow[r];
          if (c == 0) m *= ml;
          if (c == 2) m *= mr;
          va[r][c] *= m;
        }
      }
    }

    __builtin_amdgcn_s_setprio(1);
#pragma unroll
    for (int jj = 0; jj < CBP; ++jj) {
      const float* wp0 = wt + ((size_t)(co0 + 2 * jj) * CIN + ci) * 9;
      const float* wp1 = wp0 + (size_t)CIN * 9;
      v2f w2[9];
#pragma unroll
      for (int t = 0; t < 9; ++t)
        w2[t] = (v2f){wp0[zoff + t], wp1[zoff + t]};   // VMEM broadcast
#pragma unroll
      for (int t = 0; t < 9; ++t) {
        const int r = t / 3, c = t - r * 3;
#pragma unroll
        for (int p = 0; p < P; ++p) {
          v2f tap = (v2f){va[p + r][c], va[p + r][c]};
          acc[jj][p] = __builtin_elementwise_fma(tap, w2[t], acc[jj][p]);
        }
      }
    }
    __builtin_amdgcn_s_setprio(0);
  }

  float* outN = out + (size_t)n * COUT * out_rows * W;
#pragma unroll
  for (int p = 0; p < P; ++p) {
    const int orow = (oy0 + yb + p) - out_y0;
    if (orow < out_rows) {
#pragma unroll
      for (int jj = 0; jj < CBP; ++jj) {
        float v0 = acc[jj][p][0], v1 = acc[jj][p][1];
        v0 = v0 < 0.f ? 0.f : v0;
        v1 = v1 < 0.f ? 0.f : v1;
        outN[((size_t)(co0 + 2 * jj) * out_rows + orow) * W + x] = v0;
        outN[((size_t)(co0 + 2 * jj + 1) * out_rows + orow) * W + x] = v1;
      }
    }
  }
}

// ---------------------------------------------------------------------------
// Scalar variant (k4, CB=25): same VMEM-weight mechanism.
// ---------------------------------------------------------------------------
template<int CIN, int COUT, int CB, int P, int W>
__global__ __launch_bounds__(256, 2) void conv3x3_relu_k(
    const float* __restrict__ in, const float* __restrict__ wt,
    float* __restrict__ out,
    int in_y0, int in_rows, int out_y0, int out_rows)
{
  static_assert(COUT % CB == 0, "CB must divide COUT");
  constexpr int NCB = COUT / CB;
  constexpr int TW  = 64;
  constexpr int TH  = 4 * P;

  const int n   = blockIdx.z / NCB;
  const int co0 = (blockIdx.z % NCB) * CB;
  const int lx  = threadIdx.x & 63;
  const int yg  = threadIdx.x >> 6;
  const int x0  = blockIdx.x * TW;
  const int x   = x0 + lx;
  const int oy0 = out_y0 + blockIdx.y * TH;
  const int yb  = yg * P;

  const int maxoff = in_rows * W * 4 - 4;

  int zoff = 0;
  asm("" : "+v"(zoff));

  int   voff[P + 2][3];
  float mrow[P + 2];
#pragma unroll
  for (int r = 0; r < P + 2; ++r) {
    int ry = oy0 + yb + r - 1 - in_y0;
    mrow[r] = (ry >= 0 && ry < in_rows) ? 1.f : 0.f;
    int ryc = ry < 0 ? 0 : (ry >= in_rows ? in_rows - 1 : ry);
    int vo  = (ryc * W + x) * 4;
    voff[r][1] = vo;
    voff[r][0] = (vo > 4 ? vo : 4) - 4;
    int vr = vo + 4;
    voff[r][2] = vr < maxoff ? vr : maxoff;
  }
  const float ml = (x == 0)     ? 0.f : 1.f;
  const float mr = (x == W - 1) ? 0.f : 1.f;

  const bool interior =
      (x0 > 0) && (x0 + TW < W) &&
      ((oy0 - 1 - in_y0) >= 0) && ((oy0 + TH - in_y0) < in_rows);

  float acc[CB][P];
#pragma unroll
  for (int j = 0; j < CB; ++j)
#pragma unroll
    for (int p = 0; p < P; ++p) acc[j][p] = 0.f;

  const float* inN = in + (size_t)n * CIN * in_rows * W;
  const size_t chbytes = (size_t)in_rows * W * 4;

#pragma unroll 1
  for (int ci = 0; ci < CIN; ++ci) {
    const char* bp = (const char*)inN + (size_t)ci * chbytes;

    float va[P + 2][3];
#pragma unroll
    for (int r = 0; r < P + 2; ++r)
#pragma unroll
      for (int c = 0; c < 3; ++c)
        va[r][c] = *(const float*)(bp + voff[r][c]);

    if (!interior) {
#pragma unroll
      for (int r = 0; r < P + 2; ++r) {
#pragma unroll
        for (int c = 0; c < 3; ++c) {
          float m = mrow[r];
          if (c == 0) m *= ml;
          if (c == 2) m *= mr;
          va[r][c] *= m;
        }
      }
    }

    __builtin_amdgcn_s_setprio(1);
#pragma unroll
    for (int j = 0; j < CB; ++j) {
      const float* wp = wt + ((size_t)(co0 + j) * CIN + ci) * 9;
      float w[9];
#pragma unroll
      for (int t = 0; t < 9; ++t) w[t] = wp[zoff + t];   // VMEM broadcast
#pragma unroll
      for (int t = 0; t < 9; ++t) {
        const int r = t / 3, c = t - r * 3;
#pragma unroll
        for (int p = 0; p < P; ++p)
          acc[j][p] = fmaf(va[p + r][c], w[t], acc[j][p]);
      }
    }
    __builtin_amdgcn_s_setprio(0);
  }

  float* outN = out + (size_t)n * COUT * out_rows * W;
#pragma unroll
  for (int p = 0; p < P; ++p) {
    const int orow = (oy0 + yb + p) - out_y0;
    if (orow < out_rows) {
#pragma unroll
      for (int j = 0; j < CB; ++j) {
        float v = acc[j][p] < 0.f ? 0.f : acc[j][p];
        outN[((size_t)(co0 + j) * out_rows + orow) * W + x] = v;
      }
    }
  }
}

// ---------------------------------------------------------------------------
// PixelShuffle r=4 + ReLU, BOTH images: (2,16,256,256) -> (2,1024,1024)
// ---------------------------------------------------------------------------
__global__ __launch_bounds__(256) void pixel_shuffle_relu_k(
    const float* __restrict__ in, float* __restrict__ out)
{
  int i = blockIdx.x * 256 + threadIdx.x;
  int n = i >> 20;
  int p = i & 1048575;
  int x = p & 1023, y = p >> 10;
  int c = (y & 3) * 4 + (x & 3);
  float v = in[((size_t)(n * 16 + c) * 256 + (y >> 2)) * 256 + (x >> 2)];
  out[i] = v < 0.f ? 0.f : v;
}

// ---------------------------------------------------------------------------
// Per-pixel 5x5 dynamic conv + residual (unchanged).
// ---------------------------------------------------------------------------
__global__ __launch_bounds__(256) void pixel_conv_add_k(
    const float* __restrict__ h,
    const float* __restrict__ ker,
    float* __restrict__ out,
    int ky0, int krows)
{
  const int tx = threadIdx.x & 15, ty = threadIdx.x >> 4;
  const int x0 = blockIdx.x * 16;
  const int y0 = ky0 + blockIdx.y * 16;

  __shared__ float tile[20][21];
  for (int t = threadIdx.x; t < 20 * 20; t += 256) {
    int r = t / 20, c = t - r * 20;
    int yy = y0 + r - 2, xx = x0 + c - 2;
    float v = 0.f;
    if (yy >= 0 && yy < 1024 && xx >= 0 && xx < 1024) v = h[(size_t)yy * 1024 + xx];
    tile[r][c] = v;
  }
  __syncthreads();

  const int x = x0 + tx, y = y0 + ty;
  float acc = tile[ty + 2][tx + 2];
  const size_t kpix = (size_t)(y - ky0) * 1024 + x;
#pragma unroll
  for (int kw = 0; kw < 5; ++kw) {
#pragma unroll
    for (int kh = 0; kh < 5; ++kh) {
      float kv = ker[(size_t)(kw * 5 + kh) * krows * 1024 + kpix];
      acc = fmaf(tile[ty + kh][tx + kw], kv, acc);
    }
  }
  out[(size_t)y * 1024 + x] = acc;
}

// ---------------------------------------------------------------------------
// Launch (identical structure to v16).
// ---------------------------------------------------------------------------
extern "C" void kernel_launch(void* const* d_in, const int* in_sizes, int n_in,
                              void* d_out, int out_size, void* d_ws, size_t ws_size,
                              hipStream_t stream) {
  const float* x    = (const float*)d_in[0];
  const float* w_e1 = (const float*)d_in[1];
  const float* w_e2 = (const float*)d_in[2];
  const float* w_e3 = (const float*)d_in[3];
  const float* w_d1 = (const float*)d_in[4];
  const float* w_d2 = (const float*)d_in[5];
  const float* w_k1 = (const float*)d_in[6];
  const float* w_k2 = (const float*)d_in[7];
  const float* w_k3 = (const float*)d_in[8];
  const float* w_k4 = (const float*)d_in[9];

  const size_t HS_SZ = 8388608;
  const size_t AMIN  = 16777216;
  const size_t BMIN  = 33554432;

  int S = 64;
  {
    const int cand[5] = {1024, 512, 256, 128, 64};
    for (int i = 0; i < 5; ++i) {
      int s = cand[i];
      size_t a = 32ull * (size_t)(s + 6) * 1024 * 4; if (a < AMIN) a = AMIN;
      size_t b = 64ull * (size_t)(s + 4) * 1024 * 4; if (b < BMIN) b = BMIN;
      if (HS_SZ + a + b <= ws_size) { S = s; break; }
    }
  }
  size_t A_SZ = 32ull * (size_t)(S + 6) * 1024 * 4; if (A_SZ < AMIN) A_SZ = AMIN;

  char* ws = (char*)d_ws;
  float* Hs = (float*)(ws);
  float* A  = (float*)(ws + HS_SZ);
  float* B  = (float*)(ws + HS_SZ + A_SZ);
  float* outp = (float*)d_out;

  dim3 blk(256);

  // ---- encoder/decoder @256², both images, packed conv ----
  conv3x3_relu_pk<1, 16, 16, 4, 256><<<dim3(4, 16, 2), blk, 0, stream>>>(x, w_e1, B, 0, 256, 0, 256);
  conv3x3_relu_pk<16, 32, 16, 4, 256><<<dim3(4, 16, 4), blk, 0, stream>>>(B, w_e2, A, 0, 256, 0, 256);
  conv3x3_relu_pk<32, 64, 16, 4, 256><<<dim3(4, 16, 8), blk, 0, stream>>>(A, w_e3, B, 0, 256, 0, 256);
  conv3x3_relu_pk<64, 32, 16, 4, 256><<<dim3(4, 16, 4), blk, 0, stream>>>(B, w_d1, A, 0, 256, 0, 256);
  conv3x3_relu_pk<32, 16, 16, 4, 256><<<dim3(4, 16, 2), blk, 0, stream>>>(A, w_d2, B, 0, 256, 0, 256);
  pixel_shuffle_relu_k<<<dim3(8192), blk, 0, stream>>>(B, Hs);

  // ---- kernel-prediction branch + dynamic conv, per image, row strips ----
  const int nstr = 1024 / S;
  for (int n = 0; n < 2; ++n) {
    const float* himg = Hs + (size_t)n * 1048576;
    float* outn = outp + (size_t)n * 1048576;
    for (int s = 0; s < nstr; ++s) {
      const int r0 = s * S, r1 = r0 + S;
      const int z1y0 = (r0 - 3 > 0) ? r0 - 3 : 0;
      const int z1r  = ((r1 + 3 < 1024) ? r1 + 3 : 1024) - z1y0;
      const int z2y0 = (r0 - 2 > 0) ? r0 - 2 : 0;
      const int z2r  = ((r1 + 2 < 1024) ? r1 + 2 : 1024) - z2y0;
      const int z3y0 = (r0 - 1 > 0) ? r0 - 1 : 0;
      const int z3r  = ((r1 + 1 < 1024) ? r1 + 1 : 1024) - z3y0;
      const int g1 = (z1r + 15) / 16, g2 = (z2r + 15) / 16, g3 = (z3r + 15) / 16;

      conv3x3_relu_pk<1, 32, 16, 4, 1024><<<dim3(16, g1, 2), blk, 0, stream>>>(
          himg, w_k1, A, 0, 1024, z1y0, z1r);
      conv3x3_relu_pk<32, 64, 16, 4, 1024><<<dim3(16, g2, 4), blk, 0, stream>>>(
          A, w_k2, B, z1y0, z1r, z2y0, z2r);
      conv3x3_relu_pk<64, 32, 16, 4, 1024><<<dim3(16, g3, 2), blk, 0, stream>>>(
          B, w_k3, A, z2y0, z2r, z3y0, z3r);
      conv3x3_relu_k<32, 25, 25, 4, 1024><<<dim3(16, S / 16, 1), blk, 0, stream>>>(
          A, w_k4, B, z3y0, z3r, r0, S);
      pixel_conv_add_k<<<dim3(64, S / 16), blk, 0, stream>>>(
          himg, B, outn, r0, S);
    }
  }
}

// Round 18
// 2660.360 us; speedup vs baseline: 1.5839x; 1.5839x over previous
//
#include <hip/hip_runtime.h>

// ---------------------------------------------------------------------------
// v18 = v16 VERBATIM (best verified: 2682us) — restoration after v17's
// VMEM-weight experiment regressed (272 -> 468us/dispatch).
//
// Weight-path mechanism space, fully measured (us per k2-class dispatch):
//   native s_load (this kernel): 272  <- compiler's schedule is optimal
//   VMEM broadcast (r17):        468
//   [co_blk][ci][j][9] repack (r7), ci-pair w[18] clump (r12): 506-583
//   LDS staged (r4):             556
// Other dead ends: tap prefetch (r3/r9), k4+pixconv fusion (r8),
// convoy barrier (r11), P=6 (r13), packed CB=25 k4 (r15).
// Wins kept: P=4 (r6), setprio (r14, +1%), f32x2 j-packing even-CB (r16).
//
// Structural constraint at this plateau: weights travel the SMEM path;
// s_load returns are unordered -> coarse lgkmcnt drains with ~4-group
// look-ahead bound the VALU at ~55% busy (measured FMA floor 123us vs 272
// actual on k2). Every source-level restructuring of that path measured
// slower. 5934 -> 2682us this session (2.21x).
// ---------------------------------------------------------------------------

typedef float v2f __attribute__((ext_vector_type(2)));

// ---------------------------------------------------------------------------
// Packed variant: CB even. CB/2 j-pairs of 2x9 wave-uniform s_load weights
// feeding P*9 v_pk_fma_f32 each. Weight s_load addresses/order = v10/v14.
// ---------------------------------------------------------------------------
template<int CIN, int COUT, int CB, int P, int W>
__global__ __launch_bounds__(256, 2) void conv3x3_relu_pk(
    const float* __restrict__ in, const float* __restrict__ wt,
    float* __restrict__ out,
    int in_y0, int in_rows, int out_y0, int out_rows)
{
  static_assert(COUT % CB == 0 && (CB & 1) == 0, "even CB dividing COUT");
  constexpr int NCB = COUT / CB;
  constexpr int TW  = 64;
  constexpr int TH  = 4 * P;
  constexpr int CBP = CB / 2;

  const int n   = blockIdx.z / NCB;
  const int co0 = (blockIdx.z % NCB) * CB;
  const int lx  = threadIdx.x & 63;
  const int yg  = threadIdx.x >> 6;
  const int x0  = blockIdx.x * TW;
  const int x   = x0 + lx;
  const int oy0 = out_y0 + blockIdx.y * TH;
  const int yb  = yg * P;

  const int maxoff = in_rows * W * 4 - 4;

  int   voff[P + 2][3];
  float mrow[P + 2];
#pragma unroll
  for (int r = 0; r < P + 2; ++r) {
    int ry = oy0 + yb + r - 1 - in_y0;
    mrow[r] = (ry >= 0 && ry < in_rows) ? 1.f : 0.f;
    int ryc = ry < 0 ? 0 : (ry >= in_rows ? in_rows - 1 : ry);
    int vo  = (ryc * W + x) * 4;
    voff[r][1] = vo;
    voff[r][0] = (vo > 4 ? vo : 4) - 4;
    int vr = vo + 4;
    voff[r][2] = vr < maxoff ? vr : maxoff;
  }
  const float ml = (x == 0)     ? 0.f : 1.f;
  const float mr = (x == W - 1) ? 0.f : 1.f;

  const bool interior =
      (x0 > 0) && (x0 + TW < W) &&
      ((oy0 - 1 - in_y0) >= 0) && ((oy0 + TH - in_y0) < in_rows);

  v2f acc[CBP][P];
#pragma unroll
  for (int jj = 0; jj < CBP; ++jj)
#pragma unroll
    for (int p = 0; p < P; ++p) acc[jj][p] = (v2f){0.f, 0.f};

  const float* inN = in + (size_t)n * CIN * in_rows * W;
  const size_t chbytes = (size_t)in_rows * W * 4;

#pragma unroll 1
  for (int ci = 0; ci < CIN; ++ci) {
    const char* bp = (const char*)inN + (size_t)ci * chbytes;

    float va[P + 2][3];
#pragma unroll
    for (int r = 0; r < P + 2; ++r)
#pragma unroll
      for (int c = 0; c < 3; ++c)
        va[r][c] = *(const float*)(bp + voff[r][c]);

    if (!interior) {
#pragma unroll
      for (int r = 0; r < P + 2; ++r) {
#pragma unroll
        for (int c = 0; c < 3; ++c) {
          float m = mrow[r];
          if (c == 0) m *= ml;
          if (c == 2) m *= mr;
          va[r][c] *= m;
        }
      }
    }

    __builtin_amdgcn_s_setprio(1);
#pragma unroll
    for (int jj = 0; jj < CBP; ++jj) {
      const float* wp0 = wt + ((size_t)(co0 + 2 * jj) * CIN + ci) * 9;
      const float* wp1 = wp0 + (size_t)CIN * 9;
      v2f w2[9];
#pragma unroll
      for (int t = 0; t < 9; ++t) w2[t] = (v2f){wp0[t], wp1[t]};
#pragma unroll
      for (int t = 0; t < 9; ++t) {
        const int r = t / 3, c = t - r * 3;
#pragma unroll
        for (int p = 0; p < P; ++p) {
          v2f tap = (v2f){va[p + r][c], va[p + r][c]};
          acc[jj][p] = __builtin_elementwise_fma(tap, w2[t], acc[jj][p]);
        }
      }
    }
    __builtin_amdgcn_s_setprio(0);
  }

  float* outN = out + (size_t)n * COUT * out_rows * W;
#pragma unroll
  for (int p = 0; p < P; ++p) {
    const int orow = (oy0 + yb + p) - out_y0;
    if (orow < out_rows) {
#pragma unroll
      for (int jj = 0; jj < CBP; ++jj) {
        float v0 = acc[jj][p][0], v1 = acc[jj][p][1];
        v0 = v0 < 0.f ? 0.f : v0;
        v1 = v1 < 0.f ? 0.f : v1;
        outN[((size_t)(co0 + 2 * jj) * out_rows + orow) * W + x] = v0;
        outN[((size_t)(co0 + 2 * jj + 1) * out_rows + orow) * W + x] = v1;
      }
    }
  }
}

// ---------------------------------------------------------------------------
// Scalar variant (v14, proven): used for k4 (CB=25).
// ---------------------------------------------------------------------------
template<int CIN, int COUT, int CB, int P, int W>
__global__ __launch_bounds__(256, 2) void conv3x3_relu_k(
    const float* __restrict__ in, const float* __restrict__ wt,
    float* __restrict__ out,
    int in_y0, int in_rows, int out_y0, int out_rows)
{
  static_assert(COUT % CB == 0, "CB must divide COUT");
  constexpr int NCB = COUT / CB;
  constexpr int TW  = 64;
  constexpr int TH  = 4 * P;

  const int n   = blockIdx.z / NCB;
  const int co0 = (blockIdx.z % NCB) * CB;
  const int lx  = threadIdx.x & 63;
  const int yg  = threadIdx.x >> 6;
  const int x0  = blockIdx.x * TW;
  const int x   = x0 + lx;
  const int oy0 = out_y0 + blockIdx.y * TH;
  const int yb  = yg * P;

  const int maxoff = in_rows * W * 4 - 4;

  int   voff[P + 2][3];
  float mrow[P + 2];
#pragma unroll
  for (int r = 0; r < P + 2; ++r) {
    int ry = oy0 + yb + r - 1 - in_y0;
    mrow[r] = (ry >= 0 && ry < in_rows) ? 1.f : 0.f;
    int ryc = ry < 0 ? 0 : (ry >= in_rows ? in_rows - 1 : ry);
    int vo  = (ryc * W + x) * 4;
    voff[r][1] = vo;
    voff[r][0] = (vo > 4 ? vo : 4) - 4;
    int vr = vo + 4;
    voff[r][2] = vr < maxoff ? vr : maxoff;
  }
  const float ml = (x == 0)     ? 0.f : 1.f;
  const float mr = (x == W - 1) ? 0.f : 1.f;

  const bool interior =
      (x0 > 0) && (x0 + TW < W) &&
      ((oy0 - 1 - in_y0) >= 0) && ((oy0 + TH - in_y0) < in_rows);

  float acc[CB][P];
#pragma unroll
  for (int j = 0; j < CB; ++j)
#pragma unroll
    for (int p = 0; p < P; ++p) acc[j][p] = 0.f;

  const float* inN = in + (size_t)n * CIN * in_rows * W;
  const size_t chbytes = (size_t)in_rows * W * 4;

#pragma unroll 1
  for (int ci = 0; ci < CIN; ++ci) {
    const char* bp = (const char*)inN + (size_t)ci * chbytes;

    float va[P + 2][3];
#pragma unroll
    for (int r = 0; r < P + 2; ++r)
#pragma unroll
      for (int c = 0; c < 3; ++c)
        va[r][c] = *(const float*)(bp + voff[r][c]);

    if (!interior) {
#pragma unroll
      for (int r = 0; r < P + 2; ++r) {
#pragma unroll
        for (int c = 0; c < 3; ++c) {
          float m = mrow[r];
          if (c == 0) m *= ml;
          if (c == 2) m *= mr;
          va[r][c] *= m;
        }
      }
    }

    __builtin_amdgcn_s_setprio(1);
#pragma unroll
    for (int j = 0; j < CB; ++j) {
      const float* wp = wt + ((size_t)(co0 + j) * CIN + ci) * 9;
      float w[9];
#pragma unroll
      for (int t = 0; t < 9; ++t) w[t] = wp[t];
#pragma unroll
      for (int t = 0; t < 9; ++t) {
        const int r = t / 3, c = t - r * 3;
#pragma unroll
        for (int p = 0; p < P; ++p)
          acc[j][p] = fmaf(va[p + r][c], w[t], acc[j][p]);
      }
    }
    __builtin_amdgcn_s_setprio(0);
  }

  float* outN = out + (size_t)n * COUT * out_rows * W;
#pragma unroll
  for (int p = 0; p < P; ++p) {
    const int orow = (oy0 + yb + p) - out_y0;
    if (orow < out_rows) {
#pragma unroll
      for (int j = 0; j < CB; ++j) {
        float v = acc[j][p] < 0.f ? 0.f : acc[j][p];
        outN[((size_t)(co0 + j) * out_rows + orow) * W + x] = v;
      }
    }
  }
}

// ---------------------------------------------------------------------------
// PixelShuffle r=4 + ReLU, BOTH images: (2,16,256,256) -> (2,1024,1024)
// ---------------------------------------------------------------------------
__global__ __launch_bounds__(256) void pixel_shuffle_relu_k(
    const float* __restrict__ in, float* __restrict__ out)
{
  int i = blockIdx.x * 256 + threadIdx.x;
  int n = i >> 20;
  int p = i & 1048575;
  int x = p & 1023, y = p >> 10;
  int c = (y & 3) * 4 + (x & 3);
  float v = in[((size_t)(n * 16 + c) * 256 + (y >> 2)) * 256 + (x >> 2)];
  out[i] = v < 0.f ? 0.f : v;
}

// ---------------------------------------------------------------------------
// Per-pixel 5x5 dynamic conv + residual (unchanged).
// ---------------------------------------------------------------------------
__global__ __launch_bounds__(256) void pixel_conv_add_k(
    const float* __restrict__ h,
    const float* __restrict__ ker,
    float* __restrict__ out,
    int ky0, int krows)
{
  const int tx = threadIdx.x & 15, ty = threadIdx.x >> 4;
  const int x0 = blockIdx.x * 16;
  const int y0 = ky0 + blockIdx.y * 16;

  __shared__ float tile[20][21];
  for (int t = threadIdx.x; t < 20 * 20; t += 256) {
    int r = t / 20, c = t - r * 20;
    int yy = y0 + r - 2, xx = x0 + c - 2;
    float v = 0.f;
    if (yy >= 0 && yy < 1024 && xx >= 0 && xx < 1024) v = h[(size_t)yy * 1024 + xx];
    tile[r][c] = v;
  }
  __syncthreads();

  const int x = x0 + tx, y = y0 + ty;
  float acc = tile[ty + 2][tx + 2];
  const size_t kpix = (size_t)(y - ky0) * 1024 + x;
#pragma unroll
  for (int kw = 0; kw < 5; ++kw) {
#pragma unroll
    for (int kh = 0; kh < 5; ++kh) {
      float kv = ker[(size_t)(kw * 5 + kh) * krows * 1024 + kpix];
      acc = fmaf(tile[ty + kh][tx + kw], kv, acc);
    }
  }
  out[(size_t)y * 1024 + x] = acc;
}

// ---------------------------------------------------------------------------
// Launch (identical structure to v16).
// ---------------------------------------------------------------------------
extern "C" void kernel_launch(void* const* d_in, const int* in_sizes, int n_in,
                              void* d_out, int out_size, void* d_ws, size_t ws_size,
                              hipStream_t stream) {
  const float* x    = (const float*)d_in[0];
  const float* w_e1 = (const float*)d_in[1];
  const float* w_e2 = (const float*)d_in[2];
  const float* w_e3 = (const float*)d_in[3];
  const float* w_d1 = (const float*)d_in[4];
  const float* w_d2 = (const float*)d_in[5];
  const float* w_k1 = (const float*)d_in[6];
  const float* w_k2 = (const float*)d_in[7];
  const float* w_k3 = (const float*)d_in[8];
  const float* w_k4 = (const float*)d_in[9];

  const size_t HS_SZ = 8388608;
  const size_t AMIN  = 16777216;
  const size_t BMIN  = 33554432;

  int S = 64;
  {
    const int cand[5] = {1024, 512, 256, 128, 64};
    for (int i = 0; i < 5; ++i) {
      int s = cand[i];
      size_t a = 32ull * (size_t)(s + 6) * 1024 * 4; if (a < AMIN) a = AMIN;
      size_t b = 64ull * (size_t)(s + 4) * 1024 * 4; if (b < BMIN) b = BMIN;
      if (HS_SZ + a + b <= ws_size) { S = s; break; }
    }
  }
  size_t A_SZ = 32ull * (size_t)(S + 6) * 1024 * 4; if (A_SZ < AMIN) A_SZ = AMIN;

  char* ws = (char*)d_ws;
  float* Hs = (float*)(ws);
  float* A  = (float*)(ws + HS_SZ);
  float* B  = (float*)(ws + HS_SZ + A_SZ);
  float* outp = (float*)d_out;

  dim3 blk(256);

  // ---- encoder/decoder @256², both images, packed conv ----
  conv3x3_relu_pk<1, 16, 16, 4, 256><<<dim3(4, 16, 2), blk, 0, stream>>>(x, w_e1, B, 0, 256, 0, 256);
  conv3x3_relu_pk<16, 32, 16, 4, 256><<<dim3(4, 16, 4), blk, 0, stream>>>(B, w_e2, A, 0, 256, 0, 256);
  conv3x3_relu_pk<32, 64, 16, 4, 256><<<dim3(4, 16, 8), blk, 0, stream>>>(A, w_e3, B, 0, 256, 0, 256);
  conv3x3_relu_pk<64, 32, 16, 4, 256><<<dim3(4, 16, 4), blk, 0, stream>>>(B, w_d1, A, 0, 256, 0, 256);
  conv3x3_relu_pk<32, 16, 16, 4, 256><<<dim3(4, 16, 2), blk, 0, stream>>>(A, w_d2, B, 0, 256, 0, 256);
  pixel_shuffle_relu_k<<<dim3(8192), blk, 0, stream>>>(B, Hs);

  // ---- kernel-prediction branch + dynamic conv, per image, row strips ----
  const int nstr = 1024 / S;
  for (int n = 0; n < 2; ++n) {
    const float* himg = Hs + (size_t)n * 1048576;
    float* outn = outp + (size_t)n * 1048576;
    for (int s = 0; s < nstr; ++s) {
      const int r0 = s * S, r1 = r0 + S;
      const int z1y0 = (r0 - 3 > 0) ? r0 - 3 : 0;
      const int z1r  = ((r1 + 3 < 1024) ? r1 + 3 : 1024) - z1y0;
      const int z2y0 = (r0 - 2 > 0) ? r0 - 2 : 0;
      const int z2r  = ((r1 + 2 < 1024) ? r1 + 2 : 1024) - z2y0;
      const int z3y0 = (r0 - 1 > 0) ? r0 - 1 : 0;
      const int z3r  = ((r1 + 1 < 1024) ? r1 + 1 : 1024) - z3y0;
      const int g1 = (z1r + 15) / 16, g2 = (z2r + 15) / 16, g3 = (z3r + 15) / 16;

      conv3x3_relu_pk<1, 32, 16, 4, 1024><<<dim3(16, g1, 2), blk, 0, stream>>>(
          himg, w_k1, A, 0, 1024, z1y0, z1r);
      conv3x3_relu_pk<32, 64, 16, 4, 1024><<<dim3(16, g2, 4), blk, 0, stream>>>(
          A, w_k2, B, z1y0, z1r, z2y0, z2r);
      conv3x3_relu_pk<64, 32, 16, 4, 1024><<<dim3(16, g3, 2), blk, 0, stream>>>(
          B, w_k3, A, z2y0, z2r, z3y0, z3r);
      conv3x3_relu_k<32, 25, 25, 4, 1024><<<dim3(16, S / 16, 1), blk, 0, stream>>>(
          A, w_k4, B, z3y0, z3r, r0, S);
      pixel_conv_add_k<<<dim3(64, S / 16), blk, 0, stream>>>(
          himg, B, outn, r0, S);
    }
  }
}